// Round 1
// baseline (485.376 us; speedup 1.0000x reference)
//
#include <hip/hip_runtime.h>
#include <math.h>

#define IMG_H 8192
#define IMG_W 8192

// Each thread computes 4 horizontally-contiguous pixels.
// Block = (64, 4): 256 px wide, 4 rows tall. Grid = (32, 2048).
__global__ __launch_bounds__(256) void repair_kernel(const float* __restrict__ img,
                                                     float* __restrict__ out) {
    const int x4 = (blockIdx.x * blockDim.x + threadIdx.x) * 4;   // 0..8188, aligned
    const int y  = blockIdx.y * blockDim.y + threadIdx.y;

    const float inv9 = 1.0f / 9.0f;

    // v[r][c]: 3 rows (y-1,y,y+1) x 6 cols (x4-1 .. x4+4), zero outside image.
    float v[3][6];
    #pragma unroll
    for (int r = 0; r < 3; ++r) {
        const int yy = y + r - 1;
        const bool row_valid = (yy >= 0) && (yy < IMG_H);
        if (row_valid) {
            const float* rowp = img + (size_t)yy * IMG_W;
            const float4 c = *(const float4*)(rowp + x4);
            v[r][1] = c.x; v[r][2] = c.y; v[r][3] = c.z; v[r][4] = c.w;
            v[r][0] = (x4 > 0)         ? rowp[x4 - 1] : 0.0f;
            v[r][5] = (x4 + 4 < IMG_W) ? rowp[x4 + 4] : 0.0f;
        } else {
            #pragma unroll
            for (int j = 0; j < 6; ++j) v[r][j] = 0.0f;
        }
    }

    const bool row_edge = (y == 0) || (y == IMG_H - 1);
    // neighbor count row term: (y>0) + (y<H-1)
    const float cnt_row = (float)((y > 0) + (y < IMG_H - 1));

    float res[4];
    #pragma unroll
    for (int j = 0; j < 4; ++j) {
        const int gx = x4 + j;
        const float x = v[1][j + 1];

        // --- 3x3 box mean, numpy op order: acc = acc + (tap * (1/9)),
        //     separate rounded mul and add (no fma contraction) ---
        float acc = 0.0f;
        #pragma unroll
        for (int r = 0; r < 3; ++r) {
            #pragma unroll
            for (int c = 0; c < 3; ++c) {
                acc = __fadd_rn(acc, __fmul_rn(v[r][j + c], inv9));
            }
        }

        const bool col_edge = (gx == 0) || (gx == IMG_W - 1);
        const float coeff = (row_edge && col_edge) ? 2.25f
                          : ((row_edge || col_edge) ? 1.5f : 1.0f);
        const float img_mean = __fmul_rn(acc, coeff);

        const bool mask = (x > __fmul_rn(5.0f, img_mean)) || (x > 1000.0f);

        // --- neighbor repair: nsum = ((up+down)+left)+right ---
        const float up    = v[0][j + 1];
        const float down  = v[2][j + 1];
        const float left  = v[1][j];       // already 0 when gx==0
        const float right = v[1][j + 2];   // already 0 when gx==W-1
        const float nsum  = __fadd_rn(__fadd_rn(__fadd_rn(up, down), left), right);

        const float cnt = cnt_row + (float)((gx > 0) + (gx < IMG_W - 1));
        const float repaired = floorf(__fdiv_rn(nsum, cnt));

        res[j] = mask ? repaired : x;
    }

    float4 o;
    o.x = res[0]; o.y = res[1]; o.z = res[2]; o.w = res[3];
    *(float4*)(out + (size_t)y * IMG_W + x4) = o;
}

extern "C" void kernel_launch(void* const* d_in, const int* in_sizes, int n_in,
                              void* d_out, int out_size, void* d_ws, size_t ws_size,
                              hipStream_t stream) {
    const float* img = (const float*)d_in[0];
    float* out = (float*)d_out;

    dim3 block(64, 4);
    dim3 grid(IMG_W / (64 * 4), IMG_H / 4);   // (32, 2048)
    repair_kernel<<<grid, block, 0, stream>>>(img, out);
}

// Round 3
// 480.453 us; speedup vs baseline: 1.0102x; 1.0102x over previous
//
#include <hip/hip_runtime.h>
#include <math.h>

#define IMG_H 8192
#define IMG_W 8192

typedef float vfloat4 __attribute__((ext_vector_type(4)));

// Block = (64,4) threads; each thread: 4 cols (float4) x 2 rows.
// Block tile: 256 px wide x 8 rows. Grid = (32, 1024).
__global__ __launch_bounds__(256) void repair_kernel(const float* __restrict__ img,
                                                     float* __restrict__ out) {
    const int bx = blockIdx.x, by = blockIdx.y;
    const int x4 = (bx * 64 + threadIdx.x) * 4;       // 0..8188
    const int y0 = (by * 4 + threadIdx.y) * 2;        // first of 2 output rows

    const float inv9 = 1.0f / 9.0f;

    const bool interior = (bx > 0) & (bx < (int)gridDim.x - 1) &
                          (by > 0) & (by < (int)gridDim.y - 1);

    if (interior) {
        // ---------- fast path: no borders anywhere in the 4-row window ----------
        float v[4][6];
        const float* p = img + (size_t)(y0 - 1) * IMG_W + x4;
        #pragma unroll
        for (int r = 0; r < 4; ++r) {
            const float4 c = *(const float4*)p;
            v[r][0] = p[-1];
            v[r][1] = c.x; v[r][2] = c.y; v[r][3] = c.z; v[r][4] = c.w;
            v[r][5] = p[4];
            p += IMG_W;
        }

        #pragma unroll
        for (int r = 0; r < 2; ++r) {
            float res[4];
            #pragma unroll
            for (int j = 0; j < 4; ++j) {
                // 3x3 box mean, exact reference op order (no contraction)
                float acc = 0.0f;
                #pragma unroll
                for (int rr = 0; rr < 3; ++rr)
                    #pragma unroll
                    for (int cc = 0; cc < 3; ++cc)
                        acc = __fadd_rn(acc, __fmul_rn(v[r + rr][j + cc], inv9));

                const float x = v[r + 1][j + 1];
                // coeff == 1.0 in interior (bitwise identity) -> compare vs 5*acc
                const bool mask = (x > __fmul_rn(5.0f, acc)) || (x > 1000.0f);

                const float nsum = __fadd_rn(
                    __fadd_rn(__fadd_rn(v[r][j + 1], v[r + 2][j + 1]), v[r + 1][j]),
                    v[r + 1][j + 2]);
                // cnt == 4 in interior: x*0.25 is bit-identical to x/4
                const float rep = floorf(__fmul_rn(nsum, 0.25f));

                res[j] = mask ? rep : x;
            }
            vfloat4 o;
            o.x = res[0]; o.y = res[1]; o.z = res[2]; o.w = res[3];
            __builtin_nontemporal_store(o, (vfloat4*)(out + (size_t)(y0 + r) * IMG_W + x4));
        }
    } else {
        // ---------- general path: border blocks (~6% of blocks) ----------
        #pragma unroll
        for (int r = 0; r < 2; ++r) {
            const int y = y0 + r;

            float v[3][6];
            #pragma unroll
            for (int rr = 0; rr < 3; ++rr) {
                const int yy = y + rr - 1;
                const bool row_valid = (yy >= 0) && (yy < IMG_H);
                if (row_valid) {
                    const float* rowp = img + (size_t)yy * IMG_W;
                    const float4 c = *(const float4*)(rowp + x4);
                    v[rr][1] = c.x; v[rr][2] = c.y; v[rr][3] = c.z; v[rr][4] = c.w;
                    v[rr][0] = (x4 > 0)         ? rowp[x4 - 1] : 0.0f;
                    v[rr][5] = (x4 + 4 < IMG_W) ? rowp[x4 + 4] : 0.0f;
                } else {
                    #pragma unroll
                    for (int j = 0; j < 6; ++j) v[rr][j] = 0.0f;
                }
            }

            const bool row_edge = (y == 0) || (y == IMG_H - 1);
            const float cnt_row = (float)((y > 0) + (y < IMG_H - 1));

            float res[4];
            #pragma unroll
            for (int j = 0; j < 4; ++j) {
                const int gx = x4 + j;
                const float x = v[1][j + 1];

                float acc = 0.0f;
                #pragma unroll
                for (int rr = 0; rr < 3; ++rr)
                    #pragma unroll
                    for (int cc = 0; cc < 3; ++cc)
                        acc = __fadd_rn(acc, __fmul_rn(v[rr][j + cc], inv9));

                const bool col_edge = (gx == 0) || (gx == IMG_W - 1);
                const float coeff = (row_edge && col_edge) ? 2.25f
                                  : ((row_edge || col_edge) ? 1.5f : 1.0f);
                const float img_mean = __fmul_rn(acc, coeff);

                const bool mask = (x > __fmul_rn(5.0f, img_mean)) || (x > 1000.0f);

                const float nsum = __fadd_rn(
                    __fadd_rn(__fadd_rn(v[0][j + 1], v[2][j + 1]), v[1][j]),
                    v[1][j + 2]);

                const float cnt = cnt_row + (float)((gx > 0) + (gx < IMG_W - 1));
                const float rep = floorf(__fdiv_rn(nsum, cnt));

                res[j] = mask ? rep : x;
            }
            float4 o;
            o.x = res[0]; o.y = res[1]; o.z = res[2]; o.w = res[3];
            *(float4*)(out + (size_t)y * IMG_W + x4) = o;
        }
    }
}

extern "C" void kernel_launch(void* const* d_in, const int* in_sizes, int n_in,
                              void* d_out, int out_size, void* d_ws, size_t ws_size,
                              hipStream_t stream) {
    const float* img = (const float*)d_in[0];
    float* out = (float*)d_out;

    dim3 block(64, 4);
    dim3 grid(IMG_W / 256, IMG_H / 8);   // (32, 1024)
    repair_kernel<<<grid, block, 0, stream>>>(img, out);
}

// Round 4
// 449.226 us; speedup vs baseline: 1.0805x; 1.0695x over previous
//
#include <hip/hip_runtime.h>
#include <math.h>

#define IMG_H 8192
#define IMG_W 8192
#define ROWS_PER_THREAD 8

typedef float vfloat4 __attribute__((ext_vector_type(4)));

// Block = (64,4): one wave per threadIdx.y. Each thread: 4 cols x 8 rows.
// Block tile: 256 px wide x 32 rows. Grid = (32, 256).
__global__ __launch_bounds__(256) void repair_kernel(const float* __restrict__ img,
                                                     float* __restrict__ out) {
    const int bx = blockIdx.x;
    const int lane = threadIdx.x;                    // 0..63 == full wave
    const int x4 = bx * 256 + lane * 4;
    const int y0 = (blockIdx.y * blockDim.y + threadIdx.y) * ROWS_PER_THREAD;
    const bool x_edge_blk = (bx == 0) || (bx == (int)gridDim.x - 1);

    const float inv9 = 1.0f / 9.0f;

    float w[3][6];   // rolling 3-row window: [left, c.x, c.y, c.z, c.w, right]

    auto load_row = [&](int yy, float* row) {
        if (yy >= 0 && yy < IMG_H) {                 // wave-uniform condition
            const float* rp = img + (size_t)yy * IMG_W + x4;
            const float4 c = *(const float4*)rp;
            float lw = __shfl_up(c.w, 1);            // lane i-1's last element
            float rw = __shfl_down(c.x, 1);          // lane i+1's first element
            if (lane == 0)  lw = (x4 > 0)         ? rp[-1] : 0.0f;
            if (lane == 63) rw = (x4 + 4 < IMG_W) ? rp[4]  : 0.0f;
            row[0] = lw; row[1] = c.x; row[2] = c.y; row[3] = c.z; row[4] = c.w; row[5] = rw;
        } else {
            row[0] = row[1] = row[2] = row[3] = row[4] = row[5] = 0.0f;
        }
    };

    load_row(y0 - 1, w[0]);
    load_row(y0,     w[1]);

    #pragma unroll
    for (int r = 0; r < ROWS_PER_THREAD; ++r) {
        load_row(y0 + r + 1, w[(r + 2) % 3]);
        const float* up  = w[r % 3];
        const float* mid = w[(r + 1) % 3];
        const float* dn  = w[(r + 2) % 3];
        const int y = y0 + r;

        float res[4];
        #pragma unroll
        for (int j = 0; j < 4; ++j) {
            // 3x3 box mean, exact reference op order (row-major taps, no fma)
            float acc = 0.0f;
            #pragma unroll
            for (int cc = 0; cc < 3; ++cc) acc = __fadd_rn(acc, __fmul_rn(up[j + cc],  inv9));
            #pragma unroll
            for (int cc = 0; cc < 3; ++cc) acc = __fadd_rn(acc, __fmul_rn(mid[j + cc], inv9));
            #pragma unroll
            for (int cc = 0; cc < 3; ++cc) acc = __fadd_rn(acc, __fmul_rn(dn[j + cc],  inv9));

            const float x = mid[j + 1];
            // interior: coeff==1.0 (bitwise identity), cnt==4 (x*0.25 == x/4 exactly)
            const bool mask = (x > __fmul_rn(5.0f, acc)) || (x > 1000.0f);
            const float nsum = __fadd_rn(
                __fadd_rn(__fadd_rn(up[j + 1], dn[j + 1]), mid[j]), mid[j + 2]);
            const float rep = floorf(__fmul_rn(nsum, 0.25f));
            res[j] = mask ? rep : x;
        }

        const bool row_edge = (y == 0) || (y == IMG_H - 1);
        if (x_edge_blk || row_edge) {                // wave-uniform, rare
            const float cnt_row = (float)((y > 0) + (y < IMG_H - 1));
            #pragma unroll
            for (int j = 0; j < 4; ++j) {
                const int gx = x4 + j;
                const bool col_edge = (gx == 0) || (gx == IMG_W - 1);
                if (col_edge || row_edge) {
                    float acc = 0.0f;
                    #pragma unroll
                    for (int cc = 0; cc < 3; ++cc) acc = __fadd_rn(acc, __fmul_rn(up[j + cc],  inv9));
                    #pragma unroll
                    for (int cc = 0; cc < 3; ++cc) acc = __fadd_rn(acc, __fmul_rn(mid[j + cc], inv9));
                    #pragma unroll
                    for (int cc = 0; cc < 3; ++cc) acc = __fadd_rn(acc, __fmul_rn(dn[j + cc],  inv9));

                    const float coeff = (row_edge && col_edge) ? 2.25f : 1.5f;
                    const float img_mean = __fmul_rn(acc, coeff);
                    const float x = mid[j + 1];
                    const bool mask = (x > __fmul_rn(5.0f, img_mean)) || (x > 1000.0f);
                    const float nsum = __fadd_rn(
                        __fadd_rn(__fadd_rn(up[j + 1], dn[j + 1]), mid[j]), mid[j + 2]);
                    const float cnt = cnt_row + (float)((gx > 0) + (gx < IMG_W - 1));
                    const float rep = floorf(__fdiv_rn(nsum, cnt));
                    res[j] = mask ? rep : x;
                }
            }
        }

        vfloat4 o;
        o.x = res[0]; o.y = res[1]; o.z = res[2]; o.w = res[3];
        __builtin_nontemporal_store(o, (vfloat4*)(out + (size_t)y * IMG_W + x4));
    }
}

extern "C" void kernel_launch(void* const* d_in, const int* in_sizes, int n_in,
                              void* d_out, int out_size, void* d_ws, size_t ws_size,
                              hipStream_t stream) {
    const float* img = (const float*)d_in[0];
    float* out = (float*)d_out;

    dim3 block(64, 4);
    dim3 grid(IMG_W / 256, IMG_H / (4 * ROWS_PER_THREAD));   // (32, 256)
    repair_kernel<<<grid, block, 0, stream>>>(img, out);
}